// Round 1
// baseline (3096.390 us; speedup 1.0000x reference)
//
#include <hip/hip_runtime.h>
#include <math.h>

#define TT 2048
#define CC 1024
#define HH 16
#define DD 64
#define EE 8
#define FF 4096
#define NQKV 3072

// ---------------- LayerNorm ----------------
__global__ __launch_bounds__(256) void ln_kernel(const float* __restrict__ x,
    const float* __restrict__ g, const float* __restrict__ b,
    float* __restrict__ out) {
  int t = blockIdx.x;
  const float* row = x + (size_t)t * CC;
  float s = 0.f, s2 = 0.f;
  for (int c = threadIdx.x; c < CC; c += 256) {
    float v = row[c];
    s += v; s2 += v * v;
  }
  for (int off = 32; off >= 1; off >>= 1) {
    s += __shfl_down(s, off, 64);
    s2 += __shfl_down(s2, off, 64);
  }
  __shared__ float rs[4], rs2[4];
  int w = threadIdx.x >> 6, lane = threadIdx.x & 63;
  if (lane == 0) { rs[w] = s; rs2[w] = s2; }
  __syncthreads();
  s = rs[0] + rs[1] + rs[2] + rs[3];
  s2 = rs2[0] + rs2[1] + rs2[2] + rs2[3];
  float mean = s * (1.f / CC);
  float var = s2 * (1.f / CC) - mean * mean;
  float inv = rsqrtf(var + 1e-5f);
  float* orow = out + (size_t)t * CC;
  for (int c = threadIdx.x; c < CC; c += 256) {
    float v = row[c];
    orow[c] = (v - mean) * inv * g[c] + b[c];
  }
}

// ---------------- QKV GEMM: (2048x1024)@(1024x3072), B from Wq/Wk/Wv ----------------
__global__ __launch_bounds__(256) void qkv_kernel(const float* __restrict__ A,
    const float* __restrict__ Wq, const float* __restrict__ Wk,
    const float* __restrict__ Wv, float* __restrict__ out) {
  const int n0 = blockIdx.x * 128;
  const int m0 = blockIdx.y * 128;
  __shared__ float As[16][132];
  __shared__ float Bs[16][128];
  int tid = threadIdx.x;
  int tx = tid & 15, ty = tid >> 4;
  float acc[8][8] = {};
  const float* W = (n0 < 1024) ? Wq : (n0 < 2048) ? Wk : Wv;
  int nb = n0 & 1023;
  int ka = tid & 15, ma = tid >> 4;
  int nbl = tid & 127, kb = tid >> 7;
  for (int k0 = 0; k0 < CC; k0 += 16) {
#pragma unroll
    for (int j = 0; j < 8; ++j) {
      int mm = ma + j * 16;
      As[ka][mm] = A[(size_t)(m0 + mm) * CC + k0 + ka];
    }
#pragma unroll
    for (int j = 0; j < 8; ++j) {
      int kk = kb + j * 2;
      int n = nb + nbl;
      Bs[kk][nbl] = W[((size_t)(n >> 6) * CC + k0 + kk) * DD + (n & 63)];
    }
    __syncthreads();
#pragma unroll
    for (int k = 0; k < 16; ++k) {
      float4 a0 = *(const float4*)&As[k][ty * 8];
      float4 a1 = *(const float4*)&As[k][ty * 8 + 4];
      float4 b0 = *(const float4*)&Bs[k][tx * 8];
      float4 b1 = *(const float4*)&Bs[k][tx * 8 + 4];
      float av[8] = {a0.x, a0.y, a0.z, a0.w, a1.x, a1.y, a1.z, a1.w};
      float bv[8] = {b0.x, b0.y, b0.z, b0.w, b1.x, b1.y, b1.z, b1.w};
#pragma unroll
      for (int r = 0; r < 8; ++r)
#pragma unroll
        for (int c2 = 0; c2 < 8; ++c2)
          acc[r][c2] = fmaf(av[r], bv[c2], acc[r][c2]);
    }
    __syncthreads();
  }
#pragma unroll
  for (int r = 0; r < 8; ++r) {
    int m = m0 + ty * 8 + r;
    float* orow = out + (size_t)m * NQKV + n0 + tx * 8;
#pragma unroll
    for (int c2 = 0; c2 < 8; ++c2) orow[c2] = acc[r][c2];
  }
}

// ---------------- Attention: flash-style, 1 wave per query, 4 waves/block ----------------
__global__ __launch_bounds__(256) void attn_kernel(const float* __restrict__ qkv,
    float* __restrict__ att) {
  int h = blockIdx.y;
  int t_base = blockIdx.x * 4;
  int w = threadIdx.x >> 6;
  int lane = threadIdx.x & 63;
  int t = t_base + w;
  __shared__ float Ks[64][65];
  __shared__ float Vs[64][64];
  __shared__ float qs[4][64];
  __shared__ float ps[4][64];
  qs[w][lane] = qkv[(size_t)t * NQKV + h * 64 + lane];
  float o = 0.f, mrun = -1e30f, ssum = 0.f;
  int tmax_q = t_base + 3;
  for (int s0 = 0; s0 <= tmax_q; s0 += 64) {
    __syncthreads();
#pragma unroll
    for (int j = 0; j < 16; ++j) {
      int r = (threadIdx.x >> 6) + j * 4;
      Ks[r][lane] = qkv[(size_t)(s0 + r) * NQKV + 1024 + h * 64 + lane];
      Vs[r][lane] = qkv[(size_t)(s0 + r) * NQKV + 2048 + h * 64 + lane];
    }
    __syncthreads();
    if (s0 <= t) {
      int s = s0 + lane;
      float sc = 0.f;
#pragma unroll
      for (int d = 0; d < 64; ++d) sc = fmaf(qs[w][d], Ks[lane][d], sc);
      sc *= 0.03125f;  // C^-0.5 = 1/32
      if (s > t) sc = -1e30f;
      float mx = sc;
      for (int off = 32; off >= 1; off >>= 1) mx = fmaxf(mx, __shfl_down(mx, off, 64));
      mx = __shfl(mx, 0, 64);
      float mnew = fmaxf(mrun, mx);
      float alpha = expf(mrun - mnew);
      float p = expf(sc - mnew);
      float psum = p;
      for (int off = 32; off >= 1; off >>= 1) psum += __shfl_down(psum, off, 64);
      psum = __shfl(psum, 0, 64);
      ssum = ssum * alpha + psum;
      ps[w][lane] = p;
      o *= alpha;
#pragma unroll
      for (int l = 0; l < 64; ++l) o = fmaf(ps[w][l], Vs[l][lane], o);
      mrun = mnew;
    }
  }
  att[(size_t)t * CC + h * 64 + lane] = o / ssum;
}

// ---------------- Proj GEMM + residual: out = x + att@Wproj + bproj ----------------
__global__ __launch_bounds__(256) void proj_kernel(const float* __restrict__ A,
    const float* __restrict__ B, const float* __restrict__ bias,
    const float* __restrict__ xres, float* __restrict__ out) {
  const int n0 = blockIdx.x * 128;
  const int m0 = blockIdx.y * 128;
  __shared__ float As[16][132];
  __shared__ float Bs[16][128];
  int tid = threadIdx.x;
  int tx = tid & 15, ty = tid >> 4;
  float acc[8][8] = {};
  int ka = tid & 15, ma = tid >> 4;
  int nbl = tid & 127, kb = tid >> 7;
  for (int k0 = 0; k0 < CC; k0 += 16) {
#pragma unroll
    for (int j = 0; j < 8; ++j) {
      int mm = ma + j * 16;
      As[ka][mm] = A[(size_t)(m0 + mm) * CC + k0 + ka];
    }
#pragma unroll
    for (int j = 0; j < 8; ++j) {
      int kk = kb + j * 2;
      Bs[kk][nbl] = B[(size_t)(k0 + kk) * CC + n0 + nbl];
    }
    __syncthreads();
#pragma unroll
    for (int k = 0; k < 16; ++k) {
      float4 a0 = *(const float4*)&As[k][ty * 8];
      float4 a1 = *(const float4*)&As[k][ty * 8 + 4];
      float4 b0 = *(const float4*)&Bs[k][tx * 8];
      float4 b1 = *(const float4*)&Bs[k][tx * 8 + 4];
      float av[8] = {a0.x, a0.y, a0.z, a0.w, a1.x, a1.y, a1.z, a1.w};
      float bv[8] = {b0.x, b0.y, b0.z, b0.w, b1.x, b1.y, b1.z, b1.w};
#pragma unroll
      for (int r = 0; r < 8; ++r)
#pragma unroll
        for (int c2 = 0; c2 < 8; ++c2)
          acc[r][c2] = fmaf(av[r], bv[c2], acc[r][c2]);
    }
    __syncthreads();
  }
#pragma unroll
  for (int r = 0; r < 8; ++r) {
    int m = m0 + ty * 8 + r;
    size_t base = (size_t)m * CC + n0 + tx * 8;
#pragma unroll
    for (int c2 = 0; c2 < 8; ++c2)
      out[base + c2] = xres[base + c2] + acc[r][c2] + bias[n0 + tx * 8 + c2];
  }
}

// ---------------- Router: per-token logits, noisy top-2, gates ----------------
__global__ __launch_bounds__(64) void router_kernel(const float* __restrict__ xn2,
    const float* __restrict__ Wr, const float* __restrict__ br,
    const float* __restrict__ Wn, const float* __restrict__ bn,
    const float* __restrict__ noise, int* __restrict__ topi,
    float* __restrict__ gval) {
  int t = blockIdx.x;
  int lane = threadIdx.x;
  float aL[EE] = {}, aN[EE] = {};
  const float* xr = xn2 + (size_t)t * CC;
  for (int c = lane; c < CC; c += 64) {
    float xv = xr[c];
#pragma unroll
    for (int j = 0; j < EE; ++j) {
      aL[j] = fmaf(xv, Wr[c * EE + j], aL[j]);
      aN[j] = fmaf(xv, Wn[c * EE + j], aN[j]);
    }
  }
#pragma unroll
  for (int j = 0; j < EE; ++j) {
    for (int off = 32; off >= 1; off >>= 1) {
      aL[j] += __shfl_down(aL[j], off, 64);
      aN[j] += __shfl_down(aN[j], off, 64);
    }
  }
  if (lane == 0) {
    float noisy[EE];
#pragma unroll
    for (int j = 0; j < EE; ++j) {
      float lg = aL[j] + br[j];
      float nl = aN[j] + bn[j];
      float sp = fmaxf(nl, 0.f) + log1pf(expf(-fabsf(nl)));  // stable softplus
      noisy[j] = lg + noise[t * EE + j] * sp;
    }
    int i1 = 0;
    for (int j = 1; j < EE; ++j) if (noisy[j] > noisy[i1]) i1 = j;
    int i2 = -1;
    for (int j = 0; j < EE; ++j)
      if (j != i1 && (i2 < 0 || noisy[j] > noisy[i2])) i2 = j;
    float m = noisy[i1];
    float e2 = expf(noisy[i2] - m);
    float s = 1.f + e2;
    topi[t * 2] = i1; topi[t * 2 + 1] = i2;
    gval[t * 2] = 1.f / s; gval[t * 2 + 1] = e2 / s;
  }
}

// ---------------- Count + prefix + fill expert token lists (single block) ----------------
__global__ __launch_bounds__(256) void scan_fill_kernel(const int* __restrict__ topi,
    const float* __restrict__ gval, int* __restrict__ g_cnt,
    int* __restrict__ g_off, int* __restrict__ list, float* __restrict__ gl) {
  __shared__ int scnt[EE], soff[EE], scur[EE];
  int tid = threadIdx.x;
  if (tid < EE) { scnt[tid] = 0; scur[tid] = 0; }
  __syncthreads();
  for (int t = tid; t < TT; t += 256) {
    atomicAdd(&scnt[topi[t * 2]], 1);
    atomicAdd(&scnt[topi[t * 2 + 1]], 1);
  }
  __syncthreads();
  if (tid == 0) {
    int r = 0;
    for (int e = 0; e < EE; ++e) { soff[e] = r; r += scnt[e]; }
  }
  __syncthreads();
  for (int t = tid; t < TT; t += 256) {
    for (int k = 0; k < 2; ++k) {
      int e = topi[t * 2 + k];
      int p = atomicAdd(&scur[e], 1);
      list[soff[e] + p] = t;
      gl[soff[e] + p] = gval[t * 2 + k];
    }
  }
  if (tid < EE) { g_cnt[tid] = scnt[tid]; g_off[tid] = soff[tid]; }
}

// ---------------- MoE stage 1: hidden = relu(xn2[toks]@W1[e] + b1[e]) ----------------
__global__ __launch_bounds__(256) void moe1_kernel(const float* __restrict__ xn2,
    const float* __restrict__ W1, const float* __restrict__ b1,
    const int* __restrict__ g_cnt, const int* __restrict__ g_off,
    const int* __restrict__ list, float* __restrict__ hidden) {
  int e = blockIdx.z;
  int cnt = g_cnt[e];
  int y0 = blockIdx.y * 128;
  if (y0 >= cnt) return;
  int offE = g_off[e];
  int n0 = blockIdx.x * 128;
  __shared__ int toks[128];
  __shared__ float As[16][132];
  __shared__ float Bs[16][128];
  int tid = threadIdx.x;
  if (tid < 128) {
    int i = y0 + tid;
    toks[tid] = list[offE + (i < cnt ? i : cnt - 1)];
  }
  __syncthreads();
  int tx = tid & 15, ty = tid >> 4;
  float acc[8][8] = {};
  const float* Wb = W1 + (size_t)e * CC * FF;
  int ka = tid & 15, ma = tid >> 4;
  int nbl = tid & 127, kb = tid >> 7;
  for (int k0 = 0; k0 < CC; k0 += 16) {
#pragma unroll
    for (int j = 0; j < 8; ++j) {
      int mm = ma + j * 16;
      As[ka][mm] = xn2[(size_t)toks[mm] * CC + k0 + ka];
    }
#pragma unroll
    for (int j = 0; j < 8; ++j) {
      int kk = kb + j * 2;
      Bs[kk][nbl] = Wb[(size_t)(k0 + kk) * FF + n0 + nbl];
    }
    __syncthreads();
#pragma unroll
    for (int k = 0; k < 16; ++k) {
      float4 a0 = *(const float4*)&As[k][ty * 8];
      float4 a1 = *(const float4*)&As[k][ty * 8 + 4];
      float4 b0 = *(const float4*)&Bs[k][tx * 8];
      float4 b1 = *(const float4*)&Bs[k][tx * 8 + 4];
      float av[8] = {a0.x, a0.y, a0.z, a0.w, a1.x, a1.y, a1.z, a1.w};
      float bv[8] = {b0.x, b0.y, b0.z, b0.w, b1.x, b1.y, b1.z, b1.w};
#pragma unroll
      for (int r = 0; r < 8; ++r)
#pragma unroll
        for (int c2 = 0; c2 < 8; ++c2)
          acc[r][c2] = fmaf(av[r], bv[c2], acc[r][c2]);
    }
    __syncthreads();
  }
#pragma unroll
  for (int r = 0; r < 8; ++r) {
    int i = y0 + ty * 8 + r;
    if (i < cnt) {
      float* hrow = hidden + (size_t)(offE + i) * FF + n0 + tx * 8;
      const float* brow = b1 + (size_t)e * FF + n0 + tx * 8;
#pragma unroll
      for (int c2 = 0; c2 < 8; ++c2)
        hrow[c2] = fmaxf(acc[r][c2] + brow[c2], 0.f);
    }
  }
}

// ---------------- MoE stage 2: out += gate * (hidden@W2[e] + b2[e]) ----------------
__global__ __launch_bounds__(256) void moe2_kernel(const float* __restrict__ hidden,
    const float* __restrict__ W2, const float* __restrict__ b2,
    const int* __restrict__ g_cnt, const int* __restrict__ g_off,
    const int* __restrict__ list, const float* __restrict__ gl,
    float* __restrict__ out) {
  int e = blockIdx.z;
  int cnt = g_cnt[e];
  int y0 = blockIdx.y * 128;
  if (y0 >= cnt) return;
  int offE = g_off[e];
  int n0 = blockIdx.x * 128;
  __shared__ int toks[128];
  __shared__ float gls[128];
  __shared__ int rows[128];
  __shared__ float As[16][132];
  __shared__ float Bs[16][128];
  int tid = threadIdx.x;
  if (tid < 128) {
    int i = y0 + tid;
    int ic = (i < cnt ? i : cnt - 1);
    toks[tid] = list[offE + ic];
    gls[tid] = gl[offE + ic];
    rows[tid] = offE + ic;
  }
  __syncthreads();
  int tx = tid & 15, ty = tid >> 4;
  float acc[8][8] = {};
  const float* Wb = W2 + (size_t)e * FF * CC;
  int ka = tid & 15, ma = tid >> 4;
  int nbl = tid & 127, kb = tid >> 7;
  for (int k0 = 0; k0 < FF; k0 += 16) {
#pragma unroll
    for (int j = 0; j < 8; ++j) {
      int mm = ma + j * 16;
      As[ka][mm] = hidden[(size_t)rows[mm] * FF + k0 + ka];
    }
#pragma unroll
    for (int j = 0; j < 8; ++j) {
      int kk = kb + j * 2;
      Bs[kk][nbl] = Wb[(size_t)(k0 + kk) * CC + n0 + nbl];
    }
    __syncthreads();
#pragma unroll
    for (int k = 0; k < 16; ++k) {
      float4 a0 = *(const float4*)&As[k][ty * 8];
      float4 a1 = *(const float4*)&As[k][ty * 8 + 4];
      float4 b0 = *(const float4*)&Bs[k][tx * 8];
      float4 b1 = *(const float4*)&Bs[k][tx * 8 + 4];
      float av[8] = {a0.x, a0.y, a0.z, a0.w, a1.x, a1.y, a1.z, a1.w};
      float bv[8] = {b0.x, b0.y, b0.z, b0.w, b1.x, b1.y, b1.z, b1.w};
#pragma unroll
      for (int r = 0; r < 8; ++r)
#pragma unroll
        for (int c2 = 0; c2 < 8; ++c2)
          acc[r][c2] = fmaf(av[r], bv[c2], acc[r][c2]);
    }
    __syncthreads();
  }
#pragma unroll
  for (int r = 0; r < 8; ++r) {
    int i = y0 + ty * 8 + r;
    if (i < cnt) {
      int tok = toks[ty * 8 + r];
      float gv = gls[ty * 8 + r];
      const float* brow = b2 + (size_t)e * CC + n0 + tx * 8;
      float* orow = out + (size_t)tok * CC + n0 + tx * 8;
#pragma unroll
      for (int c2 = 0; c2 < 8; ++c2)
        atomicAdd(&orow[c2], gv * (acc[r][c2] + brow[c2]));
    }
  }
}

extern "C" void kernel_launch(void* const* d_in, const int* in_sizes, int n_in,
                              void* d_out, int out_size, void* d_ws, size_t ws_size,
                              hipStream_t stream) {
  (void)in_sizes; (void)n_in; (void)out_size; (void)ws_size;
  const float* x     = (const float*)d_in[0];
  const float* noise = (const float*)d_in[1];
  const float* ln1_g = (const float*)d_in[2];
  const float* ln1_b = (const float*)d_in[3];
  const float* ln2_g = (const float*)d_in[4];
  const float* ln2_b = (const float*)d_in[5];
  const float* Wq    = (const float*)d_in[6];
  const float* Wk    = (const float*)d_in[7];
  const float* Wv    = (const float*)d_in[8];
  const float* Wproj = (const float*)d_in[9];
  const float* bproj = (const float*)d_in[10];
  const float* Wr    = (const float*)d_in[11];
  const float* br    = (const float*)d_in[12];
  const float* Wn    = (const float*)d_in[13];
  const float* bn    = (const float*)d_in[14];
  const float* W1    = (const float*)d_in[15];
  const float* b1    = (const float*)d_in[16];
  const float* W2    = (const float*)d_in[17];
  const float* b2    = (const float*)d_in[18];
  float* out = (float*)d_out;
  float* ws = (float*)d_ws;

  const size_t M1 = 1024 * 1024;
  float* xn     = ws;                 // 2M floats (xn1, later xn2)
  float* qkv    = ws + 2 * M1;        // 6M floats
  float* att    = ws + 8 * M1;        // 2M floats
  float* hidden = ws + 2 * M1;        // 16M floats, overlaps qkv+att (dead by then)
  const size_t S = 18 * M1;
  int*   topi = (int*)(ws + S);
  float* gval = ws + S + 4096;
  int*   list = (int*)(ws + S + 8192);
  float* gl   = ws + S + 12288;
  int*   gcnt = (int*)(ws + S + 16384);
  int*   goff = (int*)(ws + S + 16384 + 8);

  ln_kernel<<<TT, 256, 0, stream>>>(x, ln1_g, ln1_b, xn);
  qkv_kernel<<<dim3(NQKV / 128, TT / 128), 256, 0, stream>>>(xn, Wq, Wk, Wv, qkv);
  attn_kernel<<<dim3(TT / 4, HH), 256, 0, stream>>>(qkv, att);
  proj_kernel<<<dim3(CC / 128, TT / 128), 256, 0, stream>>>(att, Wproj, bproj, x, out);
  ln_kernel<<<TT, 256, 0, stream>>>(out, ln2_g, ln2_b, xn);
  router_kernel<<<TT, 64, 0, stream>>>(xn, Wr, br, Wn, bn, noise, topi, gval);
  scan_fill_kernel<<<1, 256, 0, stream>>>(topi, gval, gcnt, goff, list, gl);
  moe1_kernel<<<dim3(FF / 128, TT / 128, EE), 256, 0, stream>>>(xn, W1, b1, gcnt, goff, list, hidden);
  moe2_kernel<<<dim3(CC / 128, TT / 128, EE), 256, 0, stream>>>(hidden, W2, b2, gcnt, goff, list, gl, out);
}

// Round 2
// 1516.648 us; speedup vs baseline: 2.0416x; 2.0416x over previous
//
#include <hip/hip_runtime.h>
#include <hip/hip_bf16.h>
#include <math.h>

#define TT 2048
#define CC 1024
#define HH 16
#define DD 64
#define EE 8
#define FF 4096
#define NQKV 3072

typedef __attribute__((ext_vector_type(8))) short bf16x8;
typedef __attribute__((ext_vector_type(4))) float f32x4;
typedef unsigned int u32;

__device__ __forceinline__ void g2l16(const void* g, void* l) {
  __builtin_amdgcn_global_load_lds((const __attribute__((address_space(1))) u32*)g,
                                   (__attribute__((address_space(3))) u32*)l, 16, 0, 0);
}

// ---------------- LayerNorm (fp32 out + optional bf16 out) ----------------
__global__ __launch_bounds__(256) void ln_kernel(const float* __restrict__ x,
    const float* __restrict__ g, const float* __restrict__ b,
    float* __restrict__ out, __hip_bfloat16* __restrict__ obf) {
  int t = blockIdx.x;
  const float* row = x + (size_t)t * CC;
  float s = 0.f, s2 = 0.f;
  for (int c = threadIdx.x; c < CC; c += 256) {
    float v = row[c];
    s += v; s2 += v * v;
  }
  for (int off = 32; off >= 1; off >>= 1) {
    s += __shfl_down(s, off, 64);
    s2 += __shfl_down(s2, off, 64);
  }
  __shared__ float rs[4], rs2[4];
  int w = threadIdx.x >> 6, lane = threadIdx.x & 63;
  if (lane == 0) { rs[w] = s; rs2[w] = s2; }
  __syncthreads();
  s = rs[0] + rs[1] + rs[2] + rs[3];
  s2 = rs2[0] + rs2[1] + rs2[2] + rs2[3];
  float mean = s * (1.f / CC);
  float var = s2 * (1.f / CC) - mean * mean;
  float inv = rsqrtf(var + 1e-5f);
  float* orow = out + (size_t)t * CC;
  for (int c = threadIdx.x; c < CC; c += 256) {
    float v = (row[c] - mean) * inv * g[c] + b[c];
    orow[c] = v;
    if (obf) obf[(size_t)t * CC + c] = __float2bfloat16(v);
  }
}

// ---------------- transpose + cast fp32 [R][Cc] -> bf16 [Cc][R], per expert z ----------------
__global__ __launch_bounds__(256) void tr_cast_kernel(const float* __restrict__ in,
    __hip_bfloat16* __restrict__ out, int R, int Cc) {
  const float* inp = in + (size_t)blockIdx.z * R * Cc;
  __hip_bfloat16* op = out + (size_t)blockIdx.z * R * Cc;
  __shared__ float tile[32][33];
  int x = blockIdx.x * 32 + threadIdx.x;
  int ybase = blockIdx.y * 32;
#pragma unroll
  for (int j = 0; j < 32; j += 8)
    tile[threadIdx.y + j][threadIdx.x] = inp[(size_t)(ybase + threadIdx.y + j) * Cc + x];
  __syncthreads();
  int xo = ybase + threadIdx.x;
  int yob = blockIdx.x * 32;
#pragma unroll
  for (int j = 0; j < 32; j += 8)
    op[(size_t)(yob + threadIdx.y + j) * R + xo] = __float2bfloat16(tile[threadIdx.x][threadIdx.y + j]);
}

// ---------------- QKV GEMM (fp32, kept for router-selection stability) ----------------
__global__ __launch_bounds__(256) void qkv_kernel(const float* __restrict__ A,
    const float* __restrict__ Wq, const float* __restrict__ Wk,
    const float* __restrict__ Wv, float* __restrict__ out) {
  const int n0 = blockIdx.x * 128;
  const int m0 = blockIdx.y * 128;
  __shared__ float As[16][132];
  __shared__ float Bs[16][128];
  int tid = threadIdx.x;
  int tx = tid & 15, ty = tid >> 4;
  float acc[8][8] = {};
  const float* W = (n0 < 1024) ? Wq : (n0 < 2048) ? Wk : Wv;
  int nb = n0 & 1023;
  int ka = tid & 15, ma = tid >> 4;
  int nbl = tid & 127, kb = tid >> 7;
  for (int k0 = 0; k0 < CC; k0 += 16) {
#pragma unroll
    for (int j = 0; j < 8; ++j) {
      int mm = ma + j * 16;
      As[ka][mm] = A[(size_t)(m0 + mm) * CC + k0 + ka];
    }
#pragma unroll
    for (int j = 0; j < 8; ++j) {
      int kk = kb + j * 2;
      int n = nb + nbl;
      Bs[kk][nbl] = W[((size_t)(n >> 6) * CC + k0 + kk) * DD + (n & 63)];
    }
    __syncthreads();
#pragma unroll
    for (int k = 0; k < 16; ++k) {
      float4 a0 = *(const float4*)&As[k][ty * 8];
      float4 a1 = *(const float4*)&As[k][ty * 8 + 4];
      float4 b0 = *(const float4*)&Bs[k][tx * 8];
      float4 b1 = *(const float4*)&Bs[k][tx * 8 + 4];
      float av[8] = {a0.x, a0.y, a0.z, a0.w, a1.x, a1.y, a1.z, a1.w};
      float bv[8] = {b0.x, b0.y, b0.z, b0.w, b1.x, b1.y, b1.z, b1.w};
#pragma unroll
      for (int r = 0; r < 8; ++r)
#pragma unroll
        for (int c2 = 0; c2 < 8; ++c2)
          acc[r][c2] = fmaf(av[r], bv[c2], acc[r][c2]);
    }
    __syncthreads();
  }
#pragma unroll
  for (int r = 0; r < 8; ++r) {
    int m = m0 + ty * 8 + r;
    float* orow = out + (size_t)m * NQKV + n0 + tx * 8;
#pragma unroll
    for (int c2 = 0; c2 < 8; ++c2) orow[c2] = acc[r][c2];
  }
}

// ---------------- Attention: flash-style, 1 wave per query ----------------
__global__ __launch_bounds__(256) void attn_kernel(const float* __restrict__ qkv,
    float* __restrict__ att) {
  int h = blockIdx.y;
  int t_base = blockIdx.x * 4;
  int w = threadIdx.x >> 6;
  int lane = threadIdx.x & 63;
  int t = t_base + w;
  __shared__ float Ks[64][65];
  __shared__ float Vs[64][64];
  __shared__ float qs[4][64];
  __shared__ float ps[4][64];
  qs[w][lane] = qkv[(size_t)t * NQKV + h * 64 + lane];
  float o = 0.f, mrun = -1e30f, ssum = 0.f;
  int tmax_q = t_base + 3;
  for (int s0 = 0; s0 <= tmax_q; s0 += 64) {
    __syncthreads();
#pragma unroll
    for (int j = 0; j < 16; ++j) {
      int r = (threadIdx.x >> 6) + j * 4;
      Ks[r][lane] = qkv[(size_t)(s0 + r) * NQKV + 1024 + h * 64 + lane];
      Vs[r][lane] = qkv[(size_t)(s0 + r) * NQKV + 2048 + h * 64 + lane];
    }
    __syncthreads();
    if (s0 <= t) {
      int s = s0 + lane;
      float sc = 0.f;
#pragma unroll
      for (int d = 0; d < 64; ++d) sc = fmaf(qs[w][d], Ks[lane][d], sc);
      sc *= 0.03125f;
      if (s > t) sc = -1e30f;
      float mx = sc;
      for (int off = 32; off >= 1; off >>= 1) mx = fmaxf(mx, __shfl_down(mx, off, 64));
      mx = __shfl(mx, 0, 64);
      float mnew = fmaxf(mrun, mx);
      float alpha = expf(mrun - mnew);
      float p = expf(sc - mnew);
      float psum = p;
      for (int off = 32; off >= 1; off >>= 1) psum += __shfl_down(psum, off, 64);
      psum = __shfl(psum, 0, 64);
      ssum = ssum * alpha + psum;
      ps[w][lane] = p;
      o *= alpha;
#pragma unroll
      for (int l = 0; l < 64; ++l) o = fmaf(ps[w][l], Vs[l][lane], o);
      mrun = mnew;
    }
  }
  att[(size_t)t * CC + h * 64 + lane] = o / ssum;
}

// ---------------- Proj GEMM + residual (fp32) ----------------
__global__ __launch_bounds__(256) void proj_kernel(const float* __restrict__ A,
    const float* __restrict__ B, const float* __restrict__ bias,
    const float* __restrict__ xres, float* __restrict__ out) {
  const int n0 = blockIdx.x * 128;
  const int m0 = blockIdx.y * 128;
  __shared__ float As[16][132];
  __shared__ float Bs[16][128];
  int tid = threadIdx.x;
  int tx = tid & 15, ty = tid >> 4;
  float acc[8][8] = {};
  int ka = tid & 15, ma = tid >> 4;
  int nbl = tid & 127, kb = tid >> 7;
  for (int k0 = 0; k0 < CC; k0 += 16) {
#pragma unroll
    for (int j = 0; j < 8; ++j) {
      int mm = ma + j * 16;
      As[ka][mm] = A[(size_t)(m0 + mm) * CC + k0 + ka];
    }
#pragma unroll
    for (int j = 0; j < 8; ++j) {
      int kk = kb + j * 2;
      Bs[kk][nbl] = B[(size_t)(k0 + kk) * CC + n0 + nbl];
    }
    __syncthreads();
#pragma unroll
    for (int k = 0; k < 16; ++k) {
      float4 a0 = *(const float4*)&As[k][ty * 8];
      float4 a1 = *(const float4*)&As[k][ty * 8 + 4];
      float4 b0 = *(const float4*)&Bs[k][tx * 8];
      float4 b1 = *(const float4*)&Bs[k][tx * 8 + 4];
      float av[8] = {a0.x, a0.y, a0.z, a0.w, a1.x, a1.y, a1.z, a1.w};
      float bv[8] = {b0.x, b0.y, b0.z, b0.w, b1.x, b1.y, b1.z, b1.w};
#pragma unroll
      for (int r = 0; r < 8; ++r)
#pragma unroll
        for (int c2 = 0; c2 < 8; ++c2)
          acc[r][c2] = fmaf(av[r], bv[c2], acc[r][c2]);
    }
    __syncthreads();
  }
#pragma unroll
  for (int r = 0; r < 8; ++r) {
    int m = m0 + ty * 8 + r;
    size_t base = (size_t)m * CC + n0 + tx * 8;
#pragma unroll
    for (int c2 = 0; c2 < 8; ++c2)
      out[base + c2] = xres[base + c2] + acc[r][c2] + bias[n0 + tx * 8 + c2];
  }
}

// ---------------- Router (fp32 — selection must be exact vs ref) ----------------
__global__ __launch_bounds__(64) void router_kernel(const float* __restrict__ xn2,
    const float* __restrict__ Wr, const float* __restrict__ br,
    const float* __restrict__ Wn, const float* __restrict__ bn,
    const float* __restrict__ noise, int* __restrict__ topi,
    float* __restrict__ gval) {
  int t = blockIdx.x;
  int lane = threadIdx.x;
  float aL[EE] = {}, aN[EE] = {};
  const float* xr = xn2 + (size_t)t * CC;
  for (int c = lane; c < CC; c += 64) {
    float xv = xr[c];
#pragma unroll
    for (int j = 0; j < EE; ++j) {
      aL[j] = fmaf(xv, Wr[c * EE + j], aL[j]);
      aN[j] = fmaf(xv, Wn[c * EE + j], aN[j]);
    }
  }
#pragma unroll
  for (int j = 0; j < EE; ++j) {
    for (int off = 32; off >= 1; off >>= 1) {
      aL[j] += __shfl_down(aL[j], off, 64);
      aN[j] += __shfl_down(aN[j], off, 64);
    }
  }
  if (lane == 0) {
    float noisy[EE];
#pragma unroll
    for (int j = 0; j < EE; ++j) {
      float lg = aL[j] + br[j];
      float nl = aN[j] + bn[j];
      float sp = fmaxf(nl, 0.f) + log1pf(expf(-fabsf(nl)));
      noisy[j] = lg + noise[t * EE + j] * sp;
    }
    int i1 = 0;
    for (int j = 1; j < EE; ++j) if (noisy[j] > noisy[i1]) i1 = j;
    int i2 = -1;
    for (int j = 0; j < EE; ++j)
      if (j != i1 && (i2 < 0 || noisy[j] > noisy[i2])) i2 = j;
    float m = noisy[i1];
    float e2 = expf(noisy[i2] - m);
    float s = 1.f + e2;
    topi[t * 2] = i1; topi[t * 2 + 1] = i2;
    gval[t * 2] = 1.f / s; gval[t * 2 + 1] = e2 / s;
  }
}

// ---------------- Count + prefix + fill (single block) ----------------
__global__ __launch_bounds__(256) void scan_fill_kernel(const int* __restrict__ topi,
    const float* __restrict__ gval, int* __restrict__ g_cnt,
    int* __restrict__ g_off, int* __restrict__ list, float* __restrict__ gl) {
  __shared__ int scnt[EE], soff[EE], scur[EE];
  int tid = threadIdx.x;
  if (tid < EE) { scnt[tid] = 0; scur[tid] = 0; }
  __syncthreads();
  for (int t = tid; t < TT; t += 256) {
    atomicAdd(&scnt[topi[t * 2]], 1);
    atomicAdd(&scnt[topi[t * 2 + 1]], 1);
  }
  __syncthreads();
  if (tid == 0) {
    int r = 0;
    for (int e = 0; e < EE; ++e) { soff[e] = r; r += scnt[e]; }
  }
  __syncthreads();
  for (int t = tid; t < TT; t += 256) {
    for (int k = 0; k < 2; ++k) {
      int e = topi[t * 2 + k];
      int p = atomicAdd(&scur[e], 1);
      list[soff[e] + p] = t;
      gl[soff[e] + p] = gval[t * 2 + k];
    }
  }
  if (tid < EE) { g_cnt[tid] = scnt[tid]; g_off[tid] = soff[tid]; }
}

// ---------------- MoE stage 1 (bf16 MFMA): hidden = relu(xb[toks]@W1t^T + b1) ----------------
// LDS layout: As/Bs [128 rows][32 k] bf16, k-chunk XOR-swizzled: slot = chunk ^ ((row>>1)&3)
__global__ __launch_bounds__(256) void moe1_mfma(const __hip_bfloat16* __restrict__ xb,
    const __hip_bfloat16* __restrict__ Wt, const float* __restrict__ b1,
    const int* __restrict__ g_cnt, const int* __restrict__ g_off,
    const int* __restrict__ list, __hip_bfloat16* __restrict__ hidden) {
  int e = blockIdx.z;
  int cnt = g_cnt[e];
  int y0 = blockIdx.y * 128;
  if (y0 >= cnt) return;
  int offE = g_off[e];
  int n0 = blockIdx.x * 128;
  __shared__ short As[128 * 32];
  __shared__ short Bs[128 * 32];
  int tid = threadIdx.x;
  int lane = tid & 63, w = tid >> 6;
  int rl = lane >> 2, sl = lane & 3;
  int rA0 = (w * 2 + 0) * 16 + rl, rA1 = (w * 2 + 1) * 16 + rl;
  int cA0 = sl ^ ((rA0 >> 1) & 3), cA1 = sl ^ ((rA1 >> 1) & 3);
  int t0 = list[offE + min(y0 + rA0, cnt - 1)];
  int t1 = list[offE + min(y0 + rA1, cnt - 1)];
  const __hip_bfloat16* gA0 = xb + (size_t)t0 * CC + cA0 * 8;
  const __hip_bfloat16* gA1 = xb + (size_t)t1 * CC + cA1 * 8;
  const __hip_bfloat16* WtE = Wt + (size_t)e * FF * CC;
  const __hip_bfloat16* gB0 = WtE + (size_t)(n0 + rA0) * CC + cA0 * 8;
  const __hip_bfloat16* gB1 = WtE + (size_t)(n0 + rA1) * CC + cA1 * 8;
  void* lA0 = &As[(w * 2 + 0) * 512]; void* lA1 = &As[(w * 2 + 1) * 512];
  void* lB0 = &Bs[(w * 2 + 0) * 512]; void* lB1 = &Bs[(w * 2 + 1) * 512];
  int wr = w >> 1, wc = w & 1;
  int mr = lane & 15, q = lane >> 4;
  int co = (q ^ ((mr >> 1) & 3)) * 8;
  int aoff = (wr * 64 + mr) * 32 + co;
  int boff = (wc * 64 + mr) * 32 + co;
  f32x4 z = {0.f, 0.f, 0.f, 0.f};
  f32x4 acc[4][4];
#pragma unroll
  for (int i = 0; i < 4; ++i)
#pragma unroll
    for (int j = 0; j < 4; ++j) acc[i][j] = z;
  for (int k0 = 0; k0 < CC; k0 += 32) {
    __syncthreads();
    g2l16(gA0 + k0, lA0);
    g2l16(gA1 + k0, lA1);
    g2l16(gB0 + k0, lB0);
    g2l16(gB1 + k0, lB1);
    __syncthreads();
    bf16x8 a[4], b[4];
#pragma unroll
    for (int i = 0; i < 4; ++i) a[i] = *(const bf16x8*)&As[aoff + i * 512];
#pragma unroll
    for (int j = 0; j < 4; ++j) b[j] = *(const bf16x8*)&Bs[boff + j * 512];
#pragma unroll
    for (int i = 0; i < 4; ++i)
#pragma unroll
      for (int j = 0; j < 4; ++j)
        acc[i][j] = __builtin_amdgcn_mfma_f32_16x16x32_bf16(a[i], b[j], acc[i][j], 0, 0, 0);
  }
  int lr = lane >> 4;
#pragma unroll
  for (int j = 0; j < 4; ++j) {
    int n = n0 + wc * 64 + j * 16 + (lane & 15);
    float bv = b1[(size_t)e * FF + n];
#pragma unroll
    for (int i = 0; i < 4; ++i) {
#pragma unroll
      for (int r = 0; r < 4; ++r) {
        int lm = wr * 64 + i * 16 + lr * 4 + r;
        int m = y0 + lm;
        if (m < cnt)
          hidden[(size_t)(offE + m) * FF + n] = __float2bfloat16(fmaxf(acc[i][j][r] + bv, 0.f));
      }
    }
  }
}

// ---------------- MoE stage 2 (bf16 MFMA, split-K=2): out += gate*(hidden@W2t^T + b2) ----------------
__global__ __launch_bounds__(256) void moe2_mfma(const __hip_bfloat16* __restrict__ hidden,
    const __hip_bfloat16* __restrict__ Wt, const float* __restrict__ b2,
    const int* __restrict__ g_cnt, const int* __restrict__ g_off,
    const int* __restrict__ list, const float* __restrict__ gl,
    float* __restrict__ out) {
  int e = blockIdx.z;
  int cnt = g_cnt[e];
  int y0 = blockIdx.y * 128;
  if (y0 >= cnt) return;
  int offE = g_off[e];
  int n0 = (blockIdx.x & 7) * 128;
  int ks = blockIdx.x >> 3;          // 0..1, each covers K=2048
  __shared__ short As[128 * 32];
  __shared__ short Bs[128 * 32];
  __shared__ int toks[128];
  __shared__ float gls[128];
  int tid = threadIdx.x;
  if (tid < 128) {
    int ic = min(y0 + tid, cnt - 1);
    toks[tid] = list[offE + ic];
    gls[tid] = gl[offE + ic];
  }
  int lane = tid & 63, w = tid >> 6;
  int rl = lane >> 2, sl = lane & 3;
  int rA0 = (w * 2 + 0) * 16 + rl, rA1 = (w * 2 + 1) * 16 + rl;
  int cA0 = sl ^ ((rA0 >> 1) & 3), cA1 = sl ^ ((rA1 >> 1) & 3);
  int p0 = offE + min(y0 + rA0, cnt - 1);
  int p1 = offE + min(y0 + rA1, cnt - 1);
  const __hip_bfloat16* gA0 = hidden + (size_t)p0 * FF + ks * 2048 + cA0 * 8;
  const __hip_bfloat16* gA1 = hidden + (size_t)p1 * FF + ks * 2048 + cA1 * 8;
  const __hip_bfloat16* WtE = Wt + (size_t)e * CC * FF;
  const __hip_bfloat16* gB0 = WtE + (size_t)(n0 + rA0) * FF + ks * 2048 + cA0 * 8;
  const __hip_bfloat16* gB1 = WtE + (size_t)(n0 + rA1) * FF + ks * 2048 + cA1 * 8;
  void* lA0 = &As[(w * 2 + 0) * 512]; void* lA1 = &As[(w * 2 + 1) * 512];
  void* lB0 = &Bs[(w * 2 + 0) * 512]; void* lB1 = &Bs[(w * 2 + 1) * 512];
  int wr = w >> 1, wc = w & 1;
  int mr = lane & 15, q = lane >> 4;
  int co = (q ^ ((mr >> 1) & 3)) * 8;
  int aoff = (wr * 64 + mr) * 32 + co;
  int boff = (wc * 64 + mr) * 32 + co;
  f32x4 z = {0.f, 0.f, 0.f, 0.f};
  f32x4 acc[4][4];
#pragma unroll
  for (int i = 0; i < 4; ++i)
#pragma unroll
    for (int j = 0; j < 4; ++j) acc[i][j] = z;
  for (int k0 = 0; k0 < 2048; k0 += 32) {
    __syncthreads();
    g2l16(gA0 + k0, lA0);
    g2l16(gA1 + k0, lA1);
    g2l16(gB0 + k0, lB0);
    g2l16(gB1 + k0, lB1);
    __syncthreads();
    bf16x8 a[4], b[4];
#pragma unroll
    for (int i = 0; i < 4; ++i) a[i] = *(const bf16x8*)&As[aoff + i * 512];
#pragma unroll
    for (int j = 0; j < 4; ++j) b[j] = *(const bf16x8*)&Bs[boff + j * 512];
#pragma unroll
    for (int i = 0; i < 4; ++i)
#pragma unroll
      for (int j = 0; j < 4; ++j)
        acc[i][j] = __builtin_amdgcn_mfma_f32_16x16x32_bf16(a[i], b[j], acc[i][j], 0, 0, 0);
  }
  int lr = lane >> 4;
#pragma unroll
  for (int j = 0; j < 4; ++j) {
    int n = n0 + wc * 64 + j * 16 + (lane & 15);
    float b2v = (ks == 0) ? b2[(size_t)e * CC + n] : 0.f;
#pragma unroll
    for (int i = 0; i < 4; ++i) {
#pragma unroll
      for (int r = 0; r < 4; ++r) {
        int lm = wr * 64 + i * 16 + lr * 4 + r;
        int m = y0 + lm;
        if (m < cnt) {
          int tok = toks[lm];
          float gv = gls[lm];
          atomicAdd(&out[(size_t)tok * CC + n], gv * (acc[i][j][r] + b2v));
        }
      }
    }
  }
}

extern "C" void kernel_launch(void* const* d_in, const int* in_sizes, int n_in,
                              void* d_out, int out_size, void* d_ws, size_t ws_size,
                              hipStream_t stream) {
  (void)in_sizes; (void)n_in; (void)out_size; (void)ws_size;
  const float* x     = (const float*)d_in[0];
  const float* noise = (const float*)d_in[1];
  const float* ln1_g = (const float*)d_in[2];
  const float* ln1_b = (const float*)d_in[3];
  const float* ln2_g = (const float*)d_in[4];
  const float* ln2_b = (const float*)d_in[5];
  const float* Wq    = (const float*)d_in[6];
  const float* Wk    = (const float*)d_in[7];
  const float* Wv    = (const float*)d_in[8];
  const float* Wproj = (const float*)d_in[9];
  const float* bproj = (const float*)d_in[10];
  const float* Wr    = (const float*)d_in[11];
  const float* br    = (const float*)d_in[12];
  const float* Wn    = (const float*)d_in[13];
  const float* bn    = (const float*)d_in[14];
  const float* W1    = (const float*)d_in[15];
  const float* b1    = (const float*)d_in[16];
  const float* W2    = (const float*)d_in[17];
  const float* b2    = (const float*)d_in[18];
  float* out = (float*)d_out;
  float* ws = (float*)d_ws;

  const size_t M1 = 1024 * 1024;
  float* xn  = ws;                                        // [0, 2M) fp32
  float* qkv = ws + 2 * M1;                               // [2M, 8M) fp32
  float* att = ws + 8 * M1;                               // [8M,10M) fp32
  __hip_bfloat16* hidden = (__hip_bfloat16*)(ws + 2 * M1);   // [2M,10M) — reuses qkv+att after proj
  __hip_bfloat16* xn2b   = (__hip_bfloat16*)(ws + 10 * M1);  // [10M,11M)
  __hip_bfloat16* Wt     = (__hip_bfloat16*)(ws + 11 * M1);  // [11M,27M) 64MB shared W1t/W2t
  float* S = ws + 28 * M1;
  int*   topi = (int*)S;
  float* gval = S + 4096;
  int*   list = (int*)(S + 8192);
  float* gl   = S + 12288;
  int*   gcnt = (int*)(S + 16384);
  int*   goff = gcnt + 8;

  // W1t[e][f][c] = W1[e][c][f]  (bf16)
  tr_cast_kernel<<<dim3(FF / 32, CC / 32, EE), dim3(32, 8), 0, stream>>>(W1, Wt, CC, FF);
  ln_kernel<<<TT, 256, 0, stream>>>(x, ln1_g, ln1_b, xn, nullptr);
  qkv_kernel<<<dim3(NQKV / 128, TT / 128), 256, 0, stream>>>(xn, Wq, Wk, Wv, qkv);
  attn_kernel<<<dim3(TT / 4, HH), 256, 0, stream>>>(qkv, att);
  proj_kernel<<<dim3(CC / 128, TT / 128), 256, 0, stream>>>(att, Wproj, bproj, x, out);
  ln_kernel<<<TT, 256, 0, stream>>>(out, ln2_g, ln2_b, xn, xn2b);
  router_kernel<<<TT, 64, 0, stream>>>(xn, Wr, br, Wn, bn, noise, topi, gval);
  scan_fill_kernel<<<1, 256, 0, stream>>>(topi, gval, gcnt, goff, list, gl);
  moe1_mfma<<<dim3(FF / 128, TT / 128, EE), 256, 0, stream>>>(xn2b, Wt, b1, gcnt, goff, list, hidden);
  // W2t[e][c][f] = W2[e][f][c]  (bf16) — reuses Wt buffer after moe1 consumed W1t
  tr_cast_kernel<<<dim3(CC / 32, FF / 32, EE), dim3(32, 8), 0, stream>>>(W2, Wt, FF, CC);
  moe2_mfma<<<dim3(16, TT / 128, EE), 256, 0, stream>>>(hidden, Wt, b2, gcnt, goff, list, gl, out);
}

// Round 3
// 746.781 us; speedup vs baseline: 4.1463x; 2.0309x over previous
//
#include <hip/hip_runtime.h>
#include <hip/hip_bf16.h>
#include <math.h>

#define TT 2048
#define CC 1024
#define HH 16
#define DD 64
#define EE 8
#define FF 4096

typedef __attribute__((ext_vector_type(8))) short bf16x8;
typedef __attribute__((ext_vector_type(4))) float f32x4;
typedef unsigned int u32;
typedef __hip_bfloat16 bf16;

__device__ __forceinline__ void g2l16(const void* g, void* l) {
  __builtin_amdgcn_global_load_lds((const __attribute__((address_space(1))) u32*)g,
                                   (__attribute__((address_space(3))) u32*)l, 16, 0, 0);
}

__device__ __forceinline__ void split2(float v, bf16& h, bf16& l) {
  h = __float2bfloat16(v);
  l = __float2bfloat16(v - __bfloat162float(h));
}

// ---------------- LayerNorm: fp32 in, optional bf16 / hi+lo outputs ----------------
__global__ __launch_bounds__(256) void ln_kernel(const float* __restrict__ x,
    const float* __restrict__ g, const float* __restrict__ b,
    bf16* __restrict__ obf, bf16* __restrict__ ohi, bf16* __restrict__ olo) {
  int t = blockIdx.x;
  const float* row = x + (size_t)t * CC;
  float s = 0.f, s2 = 0.f;
  for (int c = threadIdx.x; c < CC; c += 256) {
    float v = row[c];
    s += v; s2 += v * v;
  }
  for (int off = 32; off >= 1; off >>= 1) {
    s += __shfl_down(s, off, 64);
    s2 += __shfl_down(s2, off, 64);
  }
  __shared__ float rs[4], rs2[4];
  int w = threadIdx.x >> 6, lane = threadIdx.x & 63;
  if (lane == 0) { rs[w] = s; rs2[w] = s2; }
  __syncthreads();
  s = rs[0] + rs[1] + rs[2] + rs[3];
  s2 = rs2[0] + rs2[1] + rs2[2] + rs2[3];
  float mean = s * (1.f / CC);
  float var = s2 * (1.f / CC) - mean * mean;
  float inv = rsqrtf(var + 1e-5f);
  for (int c = threadIdx.x; c < CC; c += 256) {
    float v = (row[c] - mean) * inv * g[c] + b[c];
    size_t idx = (size_t)t * CC + c;
    if (obf) obf[idx] = __float2bfloat16(v);
    if (ohi) { bf16 h, l; split2(v, h, l); ohi[idx] = h; olo[idx] = l; }
  }
}

// ---------------- transpose + split: fp32 [R][Cc] -> hi/lo bf16 [Cc][R], batched ----------------
__global__ __launch_bounds__(256) void trsplit_kernel(const float* __restrict__ in,
    bf16* __restrict__ oh, bf16* __restrict__ ol, int R, int Cc,
    long ibs, long obs) {
  in += (size_t)blockIdx.z * ibs;
  oh += (size_t)blockIdx.z * obs;
  ol += (size_t)blockIdx.z * obs;
  __shared__ float tile[32][33];
  int x = blockIdx.x * 32 + threadIdx.x;
  int ybase = blockIdx.y * 32;
#pragma unroll
  for (int j = 0; j < 32; j += 8)
    tile[threadIdx.y + j][threadIdx.x] = in[(size_t)(ybase + threadIdx.y + j) * Cc + x];
  __syncthreads();
  int xo = ybase + threadIdx.x;
  int yob = blockIdx.x * 32;
#pragma unroll
  for (int j = 0; j < 32; j += 8) {
    float v = tile[threadIdx.x][threadIdx.y + j];
    bf16 h, l; split2(v, h, l);
    size_t idx = (size_t)(yob + threadIdx.y + j) * R + xo;
    oh[idx] = h; ol[idx] = l;
  }
}

// ---------------- transpose + cast fp32 [R][Cc] -> bf16 [Cc][R], per expert z ----------------
__global__ __launch_bounds__(256) void tr_cast_kernel(const float* __restrict__ in,
    bf16* __restrict__ out, int R, int Cc) {
  const float* inp = in + (size_t)blockIdx.z * R * Cc;
  bf16* op = out + (size_t)blockIdx.z * R * Cc;
  __shared__ float tile[32][33];
  int x = blockIdx.x * 32 + threadIdx.x;
  int ybase = blockIdx.y * 32;
#pragma unroll
  for (int j = 0; j < 32; j += 8)
    tile[threadIdx.y + j][threadIdx.x] = inp[(size_t)(ybase + threadIdx.y + j) * Cc + x];
  __syncthreads();
  int xo = ybase + threadIdx.x;
  int yob = blockIdx.x * 32;
#pragma unroll
  for (int j = 0; j < 32; j += 8)
    op[(size_t)(yob + threadIdx.y + j) * R + xo] = __float2bfloat16(tile[threadIdx.x][threadIdx.y + j]);
}

// ---------------- QKV GEMM, split-bf16 MFMA (fp32-faithful) ----------------
// A = xn hi/lo [2048][1024]; B = Wqkvt hi/lo [3072][1024] (n-major, k-contig)
// epilogue: q,k natural hi/lo; v transposed -> vt[c][t] hi/lo
__global__ __launch_bounds__(256) void qkv_mfma(const bf16* __restrict__ Ahi,
    const bf16* __restrict__ Alo, const bf16* __restrict__ Bhi, const bf16* __restrict__ Blo,
    bf16* __restrict__ qhi, bf16* __restrict__ qlo, bf16* __restrict__ khi,
    bf16* __restrict__ klo, bf16* __restrict__ vthi, bf16* __restrict__ vtlo) {
  const int n0 = blockIdx.x * 128;
  const int m0 = blockIdx.y * 128;
  __shared__ short AsH[4096], AsL[4096], BsH[4096], BsL[4096];
  int tid = threadIdx.x;
  int lane = tid & 63, w = tid >> 6;
  int rl = lane >> 2, sl = lane & 3;
  int rA0 = (w * 2 + 0) * 16 + rl, rA1 = (w * 2 + 1) * 16 + rl;
  int cA0 = sl ^ ((rA0 >> 1) & 3), cA1 = sl ^ ((rA1 >> 1) & 3);
  const bf16* gA0h = Ahi + (size_t)(m0 + rA0) * CC + cA0 * 8;
  const bf16* gA1h = Ahi + (size_t)(m0 + rA1) * CC + cA1 * 8;
  const bf16* gA0l = Alo + (size_t)(m0 + rA0) * CC + cA0 * 8;
  const bf16* gA1l = Alo + (size_t)(m0 + rA1) * CC + cA1 * 8;
  const bf16* gB0h = Bhi + (size_t)(n0 + rA0) * CC + cA0 * 8;
  const bf16* gB1h = Bhi + (size_t)(n0 + rA1) * CC + cA1 * 8;
  const bf16* gB0l = Blo + (size_t)(n0 + rA0) * CC + cA0 * 8;
  const bf16* gB1l = Blo + (size_t)(n0 + rA1) * CC + cA1 * 8;
  void* lA0h = &AsH[(w * 2 + 0) * 512]; void* lA1h = &AsH[(w * 2 + 1) * 512];
  void* lA0l = &AsL[(w * 2 + 0) * 512]; void* lA1l = &AsL[(w * 2 + 1) * 512];
  void* lB0h = &BsH[(w * 2 + 0) * 512]; void* lB1h = &BsH[(w * 2 + 1) * 512];
  void* lB0l = &BsL[(w * 2 + 0) * 512]; void* lB1l = &BsL[(w * 2 + 1) * 512];
  int wr = w >> 1, wc = w & 1;
  int mr = lane & 15, q = lane >> 4;
  int co = (q ^ ((mr >> 1) & 3)) * 8;
  int aoff = (wr * 64 + mr) * 32 + co;
  int boff = (wc * 64 + mr) * 32 + co;
  f32x4 z = {0.f, 0.f, 0.f, 0.f};
  f32x4 acc[4][4];
#pragma unroll
  for (int i = 0; i < 4; ++i)
#pragma unroll
    for (int j = 0; j < 4; ++j) acc[i][j] = z;
  for (int k0 = 0; k0 < CC; k0 += 32) {
    __syncthreads();
    g2l16(gA0h + k0, lA0h); g2l16(gA1h + k0, lA1h);
    g2l16(gA0l + k0, lA0l); g2l16(gA1l + k0, lA1l);
    g2l16(gB0h + k0, lB0h); g2l16(gB1h + k0, lB1h);
    g2l16(gB0l + k0, lB0l); g2l16(gB1l + k0, lB1l);
    __syncthreads();
    bf16x8 ah[4], al[4], bh[4], bl[4];
#pragma unroll
    for (int i = 0; i < 4; ++i) {
      ah[i] = *(const bf16x8*)&AsH[aoff + i * 512];
      al[i] = *(const bf16x8*)&AsL[aoff + i * 512];
      bh[i] = *(const bf16x8*)&BsH[boff + i * 512];
      bl[i] = *(const bf16x8*)&BsL[boff + i * 512];
    }
#pragma unroll
    for (int i = 0; i < 4; ++i)
#pragma unroll
      for (int j = 0; j < 4; ++j) {
        acc[i][j] = __builtin_amdgcn_mfma_f32_16x16x32_bf16(ah[i], bh[j], acc[i][j], 0, 0, 0);
        acc[i][j] = __builtin_amdgcn_mfma_f32_16x16x32_bf16(ah[i], bl[j], acc[i][j], 0, 0, 0);
        acc[i][j] = __builtin_amdgcn_mfma_f32_16x16x32_bf16(al[i], bh[j], acc[i][j], 0, 0, 0);
      }
  }
  int lr = lane >> 4;
#pragma unroll
  for (int j = 0; j < 4; ++j) {
    int n = n0 + wc * 64 + j * 16 + mr;
#pragma unroll
    for (int i = 0; i < 4; ++i) {
#pragma unroll
      for (int r = 0; r < 4; ++r) {
        int m = m0 + wr * 64 + i * 16 + lr * 4 + r;
        bf16 h, l; split2(acc[i][j][r], h, l);
        if (n0 < 1024) {
          qhi[(size_t)m * CC + n] = h; qlo[(size_t)m * CC + n] = l;
        } else if (n0 < 2048) {
          khi[(size_t)m * CC + n - 1024] = h; klo[(size_t)m * CC + n - 1024] = l;
        } else {
          vthi[(size_t)(n - 2048) * TT + m] = h; vtlo[(size_t)(n - 2048) * TT + m] = l;
        }
      }
    }
  }
}

// ---------------- Attention: MFMA flash, split-bf16 (fp32-faithful) ----------------
// grid (32 q-tiles, 16 heads); 4 waves, each owns 16 q rows
__global__ __launch_bounds__(256) void attn_mfma(const bf16* __restrict__ qhi,
    const bf16* __restrict__ qlo, const bf16* __restrict__ khi, const bf16* __restrict__ klo,
    const bf16* __restrict__ vthi, const bf16* __restrict__ vtlo,
    bf16* __restrict__ atthi, bf16* __restrict__ attlo) {
  int qi = 31 - blockIdx.x;            // deepest blocks first
  int h = blockIdx.y;
  int qbase = qi * 64;
  int tid = threadIdx.x;
  int lane = tid & 63, w = tid >> 6;
  int mr = lane & 15, quad = lane >> 4;
  __shared__ short KsH[4096], KsL[4096], VsH[4096], VsL[4096];
  __shared__ short Ps[8192];           // [wave][hi/lo][16][64]
  // Q fragments (A-layout), resident for the whole block
  bf16x8 qfh[2], qfl[2];
#pragma unroll
  for (int ck = 0; ck < 2; ++ck) {
    size_t qo = (size_t)(qbase + w * 16 + mr) * CC + h * 64 + ck * 32 + quad * 8;
    qfh[ck] = *(const bf16x8*)(qhi + qo);
    qfl[ck] = *(const bf16x8*)(qlo + qo);
  }
  f32x4 z = {0.f, 0.f, 0.f, 0.f};
  f32x4 o[4];
#pragma unroll
  for (int jt = 0; jt < 4; ++jt) o[jt] = z;
  float ml[4] = {-1e30f, -1e30f, -1e30f, -1e30f};
  float ll[4] = {0.f, 0.f, 0.f, 0.f};
  int g = lane >> 3;
  int cnk = (lane & 7) ^ g;            // address-side chunk swizzle
  for (int s0 = 0; s0 <= qbase; s0 += 64) {
    __syncthreads();
#pragma unroll
    for (int c = w * 2; c < w * 2 + 2; ++c) {
      int row = c * 8 + g;
      g2l16(khi + (size_t)(s0 + row) * CC + h * 64 + cnk * 8, &KsH[c * 512]);
      g2l16(klo + (size_t)(s0 + row) * CC + h * 64 + cnk * 8, &KsL[c * 512]);
      g2l16(vthi + (size_t)(h * 64 + row) * TT + s0 + cnk * 8, &VsH[c * 512]);
      g2l16(vtlo + (size_t)(h * 64 + row) * TT + s0 + cnk * 8, &VsL[c * 512]);
    }
    __syncthreads();
    // S = Q K^T / 32
    f32x4 s[4];
#pragma unroll
    for (int jt = 0; jt < 4; ++jt) s[jt] = z;
#pragma unroll
    for (int jt = 0; jt < 4; ++jt)
#pragma unroll
      for (int ck = 0; ck < 2; ++ck) {
        int slot = (quad + 4 * ck) ^ (mr & 7);
        bf16x8 kh = *(const bf16x8*)&KsH[(jt * 16 + mr) * 64 + slot * 8];
        bf16x8 kl = *(const bf16x8*)&KsL[(jt * 16 + mr) * 64 + slot * 8];
        s[jt] = __builtin_amdgcn_mfma_f32_16x16x32_bf16(qfh[ck], kh, s[jt], 0, 0, 0);
        s[jt] = __builtin_amdgcn_mfma_f32_16x16x32_bf16(qfh[ck], kl, s[jt], 0, 0, 0);
        s[jt] = __builtin_amdgcn_mfma_f32_16x16x32_bf16(qfl[ck], kh, s[jt], 0, 0, 0);
      }
    bool diag = (s0 == qbase);
#pragma unroll
    for (int jt = 0; jt < 4; ++jt)
#pragma unroll
      for (int r = 0; r < 4; ++r) {
        float sc = s[jt][r] * 0.03125f;
        if (diag) {
          int key = s0 + jt * 16 + mr;
          int qrow = qbase + w * 16 + quad * 4 + r;
          if (key > qrow) sc = -1e30f;
        }
        s[jt][r] = sc;
      }
    // online softmax
    float mx[4], al[4], psum[4];
#pragma unroll
    for (int r = 0; r < 4; ++r) {
      float m0v = fmaxf(fmaxf(s[0][r], s[1][r]), fmaxf(s[2][r], s[3][r]));
#pragma unroll
      for (int msk = 1; msk <= 8; msk <<= 1) m0v = fmaxf(m0v, __shfl_xor(m0v, msk, 64));
      float mnew = fmaxf(ml[r], m0v);
      al[r] = __expf(ml[r] - mnew);
      ml[r] = mnew;
      mx[r] = mnew;
      psum[r] = 0.f;
    }
    short* PsW = &Ps[w * 2048];
#pragma unroll
    for (int jt = 0; jt < 4; ++jt)
#pragma unroll
      for (int r = 0; r < 4; ++r) {
        float p = __expf(s[jt][r] - mx[r]);
        psum[r] += p;
        bf16 ph, pl; split2(p, ph, pl);
        int mloc = quad * 4 + r;
        int col = jt * 16 + mr;
        int slot = (col >> 3) ^ (mloc & 7);
        int pa = mloc * 64 + slot * 8 + (col & 7);
        PsW[pa] = *(short*)&ph;
        PsW[1024 + pa] = *(short*)&pl;
      }
#pragma unroll
    for (int r = 0; r < 4; ++r) {
#pragma unroll
      for (int msk = 1; msk <= 8; msk <<= 1) psum[r] += __shfl_xor(psum[r], msk, 64);
      ll[r] = ll[r] * al[r] + psum[r];
#pragma unroll
      for (int jt = 0; jt < 4; ++jt) o[jt][r] *= al[r];
    }
    // P V  (P hi/lo from LDS in A-layout; V^T hi/lo in B-layout)
    bf16x8 pfh[2], pfl[2];
#pragma unroll
    for (int ck = 0; ck < 2; ++ck) {
      int slot = (quad + 4 * ck) ^ (mr & 7);
      pfh[ck] = *(const bf16x8*)&PsW[mr * 64 + slot * 8];
      pfl[ck] = *(const bf16x8*)&PsW[1024 + mr * 64 + slot * 8];
    }
#pragma unroll
    for (int jt = 0; jt < 4; ++jt)
#pragma unroll
      for (int ck = 0; ck < 2; ++ck) {
        int slot = (quad + 4 * ck) ^ (mr & 7);
        bf16x8 vh = *(const bf16x8*)&VsH[(jt * 16 + mr) * 64 + slot * 8];
        bf16x8 vl = *(const bf16x8*)&VsL[(jt * 16 + mr) * 64 + slot * 8];
        o[jt] = __builtin_amdgcn_mfma_f32_16x16x32_bf16(pfh[ck], vh, o[jt], 0, 0, 0);
        o[jt] = __builtin_amdgcn_mfma_f32_16x16x32_bf16(pfh[ck], vl, o[jt], 0, 0, 0);
        o[jt] = __builtin_amdgcn_mfma_f32_16x16x32_bf16(pfl[ck], vh, o[jt], 0, 0, 0);
      }
  }
#pragma unroll
  for (int jt = 0; jt < 4; ++jt)
#pragma unroll
    for (int r = 0; r < 4; ++r) {
      float val = o[jt][r] / ll[r];
      int row = qbase + w * 16 + quad * 4 + r;
      int col = h * 64 + jt * 16 + mr;
      bf16 hh, lo; split2(val, hh, lo);
      atthi[(size_t)row * CC + col] = hh;
      attlo[(size_t)row * CC + col] = lo;
    }
}

// ---------------- Proj GEMM split-bf16 MFMA + residual: out = x + att@Wproj + bproj ----------------
__global__ __launch_bounds__(256) void proj_mfma(const bf16* __restrict__ Ahi,
    const bf16* __restrict__ Alo, const bf16* __restrict__ Bhi, const bf16* __restrict__ Blo,
    const float* __restrict__ bias, const float* __restrict__ xres, float* __restrict__ out) {
  const int n0 = blockIdx.x * 128;
  const int m0 = blockIdx.y * 128;
  __shared__ short AsH[4096], AsL[4096], BsH[4096], BsL[4096];
  int tid = threadIdx.x;
  int lane = tid & 63, w = tid >> 6;
  int rl = lane >> 2, sl = lane & 3;
  int rA0 = (w * 2 + 0) * 16 + rl, rA1 = (w * 2 + 1) * 16 + rl;
  int cA0 = sl ^ ((rA0 >> 1) & 3), cA1 = sl ^ ((rA1 >> 1) & 3);
  const bf16* gA0h = Ahi + (size_t)(m0 + rA0) * CC + cA0 * 8;
  const bf16* gA1h = Ahi + (size_t)(m0 + rA1) * CC + cA1 * 8;
  const bf16* gA0l = Alo + (size_t)(m0 + rA0) * CC + cA0 * 8;
  const bf16* gA1l = Alo + (size_t)(m0 + rA1) * CC + cA1 * 8;
  const bf16* gB0h = Bhi + (size_t)(n0 + rA0) * CC + cA0 * 8;
  const bf16* gB1h = Bhi + (size_t)(n0 + rA1) * CC + cA1 * 8;
  const bf16* gB0l = Blo + (size_t)(n0 + rA0) * CC + cA0 * 8;
  const bf16* gB1l = Blo + (size_t)(n0 + rA1) * CC + cA1 * 8;
  void* lA0h = &AsH[(w * 2 + 0) * 512]; void* lA1h = &AsH[(w * 2 + 1) * 512];
  void* lA0l = &AsL[(w * 2 + 0) * 512]; void* lA1l = &AsL[(w * 2 + 1) * 512];
  void* lB0h = &BsH[(w * 2 + 0) * 512]; void* lB1h = &BsH[(w * 2 + 1) * 512];
  void* lB0l = &BsL[(w * 2 + 0) * 512]; void* lB1l = &BsL[(w * 2 + 1) * 512];
  int wr = w >> 1, wc = w & 1;
  int mr = lane & 15, q = lane >> 4;
  int co = (q ^ ((mr >> 1) & 3)) * 8;
  int aoff = (wr * 64 + mr) * 32 + co;
  int boff = (wc * 64 + mr) * 32 + co;
  f32x4 z = {0.f, 0.f, 0.f, 0.f};
  f32x4 acc[4][4];
#pragma unroll
  for (int i = 0; i < 4; ++i)
#pragma unroll
    for (int j = 0; j < 4; ++j) acc[i][j] = z;
  for (int k0 = 0; k0 < CC; k0 += 32) {
    __syncthreads();
    g2l16(gA0h + k0, lA0h); g2l16(gA1h + k0, lA1h);
    g2l16(gA0l + k0, lA0l); g2l16(gA1l + k0, lA1l);
    g2l16(gB0h + k0, lB0h); g2l16(gB1h + k0, lB1h);
    g2l16(gB0l + k0, lB0l); g2l16(gB1l + k0, lB1l);
    __syncthreads();
    bf16x8 ah[4], al[4], bh[4], bl[4];
#pragma unroll
    for (int i = 0; i < 4; ++i) {
      ah[i] = *(const bf16x8*)&AsH[aoff + i * 512];
      al[i] = *(const bf16x8*)&AsL[aoff + i * 512];
      bh[i] = *(const bf16x8*)&BsH[boff + i * 512];
      bl[i] = *(const bf16x8*)&BsL[boff + i * 512];
    }
#pragma unroll
    for (int i = 0; i < 4; ++i)
#pragma unroll
      for (int j = 0; j < 4; ++j) {
        acc[i][j] = __builtin_amdgcn_mfma_f32_16x16x32_bf16(ah[i], bh[j], acc[i][j], 0, 0, 0);
        acc[i][j] = __builtin_amdgcn_mfma_f32_16x16x32_bf16(ah[i], bl[j], acc[i][j], 0, 0, 0);
        acc[i][j] = __builtin_amdgcn_mfma_f32_16x16x32_bf16(al[i], bh[j], acc[i][j], 0, 0, 0);
      }
  }
  int lr = lane >> 4;
#pragma unroll
  for (int j = 0; j < 4; ++j) {
    int n = n0 + wc * 64 + j * 16 + mr;
    float bv = bias[n];
#pragma unroll
    for (int i = 0; i < 4; ++i) {
#pragma unroll
      for (int r = 0; r < 4; ++r) {
        int m = m0 + wr * 64 + i * 16 + lr * 4 + r;
        size_t idx = (size_t)m * CC + n;
        out[idx] = xres[idx] + acc[i][j][r] + bv;
      }
    }
  }
}

// ---------------- Router with fused LN2 (pure fp32 — selection must match ref) ----------------
__global__ __launch_bounds__(64) void router_kernel(const float* __restrict__ xres,
    const float* __restrict__ g, const float* __restrict__ b,
    const float* __restrict__ Wr, const float* __restrict__ br,
    const float* __restrict__ Wn, const float* __restrict__ bn,
    const float* __restrict__ noise, int* __restrict__ topi,
    float* __restrict__ gval) {
  int t = blockIdx.x;
  int lane = threadIdx.x;
  const float* row = xres + (size_t)t * CC;
  float xv[16];
  float s = 0.f, s2 = 0.f;
#pragma unroll
  for (int j = 0; j < 16; ++j) {
    xv[j] = row[lane + j * 64];
    s += xv[j]; s2 += xv[j] * xv[j];
  }
  for (int off = 32; off >= 1; off >>= 1) {
    s += __shfl_down(s, off, 64);
    s2 += __shfl_down(s2, off, 64);
  }
  s = __shfl(s, 0, 64); s2 = __shfl(s2, 0, 64);
  float mean = s * (1.f / CC);
  float inv = rsqrtf(s2 * (1.f / CC) - mean * mean + 1e-5f);
  float aL[EE] = {}, aN[EE] = {};
#pragma unroll
  for (int j = 0; j < 16; ++j) {
    int c = lane + j * 64;
    float xn = (xv[j] - mean) * inv * g[c] + b[c];
#pragma unroll
    for (int e = 0; e < EE; ++e) {
      aL[e] = fmaf(xn, Wr[c * EE + e], aL[e]);
      aN[e] = fmaf(xn, Wn[c * EE + e], aN[e]);
    }
  }
#pragma unroll
  for (int e = 0; e < EE; ++e) {
    for (int off = 32; off >= 1; off >>= 1) {
      aL[e] += __shfl_down(aL[e], off, 64);
      aN[e] += __shfl_down(aN[e], off, 64);
    }
  }
  if (lane == 0) {
    float noisy[EE];
#pragma unroll
    for (int e = 0; e < EE; ++e) {
      float lg = aL[e] + br[e];
      float nl = aN[e] + bn[e];
      float sp = fmaxf(nl, 0.f) + log1pf(expf(-fabsf(nl)));
      noisy[e] = lg + noise[t * EE + e] * sp;
    }
    int i1 = 0;
    for (int e = 1; e < EE; ++e) if (noisy[e] > noisy[i1]) i1 = e;
    int i2 = -1;
    for (int e = 0; e < EE; ++e)
      if (e != i1 && (i2 < 0 || noisy[e] > noisy[i2])) i2 = e;
    float m = noisy[i1];
    float e2 = expf(noisy[i2] - m);
    float sden = 1.f + e2;
    topi[t * 2] = i1; topi[t * 2 + 1] = i2;
    gval[t * 2] = 1.f / sden; gval[t * 2 + 1] = e2 / sden;
  }
}

// ---------------- Count + prefix + fill (single block) ----------------
__global__ __launch_bounds__(256) void scan_fill_kernel(const int* __restrict__ topi,
    const float* __restrict__ gval, int* __restrict__ g_cnt,
    int* __restrict__ g_off, int* __restrict__ list, float* __restrict__ gl) {
  __shared__ int scnt[EE], soff[EE], scur[EE];
  int tid = threadIdx.x;
  if (tid < EE) { scnt[tid] = 0; scur[tid] = 0; }
  __syncthreads();
  for (int t = tid; t < TT; t += 256) {
    atomicAdd(&scnt[topi[t * 2]], 1);
    atomicAdd(&scnt[topi[t * 2 + 1]], 1);
  }
  __syncthreads();
  if (tid == 0) {
    int r = 0;
    for (int e = 0; e < EE; ++e) { soff[e] = r; r += scnt[e]; }
  }
  __syncthreads();
  for (int t = tid; t < TT; t += 256) {
    for (int k = 0; k < 2; ++k) {
      int e = topi[t * 2 + k];
      int p = atomicAdd(&scur[e], 1);
      list[soff[e] + p] = t;
      gl[soff[e] + p] = gval[t * 2 + k];
    }
  }
  if (tid < EE) { g_cnt[tid] = scnt[tid]; g_off[tid] = soff[tid]; }
}

// ---------------- MoE stage 1 (bf16 MFMA) ----------------
__global__ __launch_bounds__(256) void moe1_mfma(const bf16* __restrict__ xb,
    const bf16* __restrict__ Wt, const float* __restrict__ b1,
    const int* __restrict__ g_cnt, const int* __restrict__ g_off,
    const int* __restrict__ list, bf16* __restrict__ hidden) {
  int e = blockIdx.z;
  int cnt = g_cnt[e];
  int y0 = blockIdx.y * 128;
  if (y0 >= cnt) return;
  int offE = g_off[e];
  int n0 = blockIdx.x * 128;
  __shared__ short As[128 * 32];
  __shared__ short Bs[128 * 32];
  int tid = threadIdx.x;
  int lane = tid & 63, w = tid >> 6;
  int rl = lane >> 2, sl = lane & 3;
  int rA0 = (w * 2 + 0) * 16 + rl, rA1 = (w * 2 + 1) * 16 + rl;
  int cA0 = sl ^ ((rA0 >> 1) & 3), cA1 = sl ^ ((rA1 >> 1) & 3);
  int t0 = list[offE + min(y0 + rA0, cnt - 1)];
  int t1 = list[offE + min(y0 + rA1, cnt - 1)];
  const bf16* gA0 = xb + (size_t)t0 * CC + cA0 * 8;
  const bf16* gA1 = xb + (size_t)t1 * CC + cA1 * 8;
  const bf16* WtE = Wt + (size_t)e * FF * CC;
  const bf16* gB0 = WtE + (size_t)(n0 + rA0) * CC + cA0 * 8;
  const bf16* gB1 = WtE + (size_t)(n0 + rA1) * CC + cA1 * 8;
  void* lA0 = &As[(w * 2 + 0) * 512]; void* lA1 = &As[(w * 2 + 1) * 512];
  void* lB0 = &Bs[(w * 2 + 0) * 512]; void* lB1 = &Bs[(w * 2 + 1) * 512];
  int wr = w >> 1, wc = w & 1;
  int mr = lane & 15, q = lane >> 4;
  int co = (q ^ ((mr >> 1) & 3)) * 8;
  int aoff = (wr * 64 + mr) * 32 + co;
  int boff = (wc * 64 + mr) * 32 + co;
  f32x4 z = {0.f, 0.f, 0.f, 0.f};
  f32x4 acc[4][4];
#pragma unroll
  for (int i = 0; i < 4; ++i)
#pragma unroll
    for (int j = 0; j < 4; ++j) acc[i][j] = z;
  for (int k0 = 0; k0 < CC; k0 += 32) {
    __syncthreads();
    g2l16(gA0 + k0, lA0);
    g2l16(gA1 + k0, lA1);
    g2l16(gB0 + k0, lB0);
    g2l16(gB1 + k0, lB1);
    __syncthreads();
    bf16x8 a[4], b[4];
#pragma unroll
    for (int i = 0; i < 4; ++i) a[i] = *(const bf16x8*)&As[aoff + i * 512];
#pragma unroll
    for (int j = 0; j < 4; ++j) b[j] = *(const bf16x8*)&Bs[boff + j * 512];
#pragma unroll
    for (int i = 0; i < 4; ++i)
#pragma unroll
      for (int j = 0; j < 4; ++j)
        acc[i][j] = __builtin_amdgcn_mfma_f32_16x16x32_bf16(a[i], b[j], acc[i][j], 0, 0, 0);
  }
  int lr = lane >> 4;
#pragma unroll
  for (int j = 0; j < 4; ++j) {
    int n = n0 + wc * 64 + j * 16 + mr;
    float bv = b1[(size_t)e * FF + n];
#pragma unroll
    for (int i = 0; i < 4; ++i) {
#pragma unroll
      for (int r = 0; r < 4; ++r) {
        int lm = wr * 64 + i * 16 + lr * 4 + r;
        int m = y0 + lm;
        if (m < cnt)
          hidden[(size_t)(offE + m) * FF + n] = __float2bfloat16(fmaxf(acc[i][j][r] + bv, 0.f));
      }
    }
  }
}

// ---------------- MoE stage 2 (bf16 MFMA, split-K=2) ----------------
__global__ __launch_bounds__(256) void moe2_mfma(const bf16* __restrict__ hidden,
    const bf16* __restrict__ Wt, const float* __restrict__ b2,
    const int* __restrict__ g_cnt, const int* __restrict__ g_off,
    const int* __restrict__ list, const float* __restrict__ gl,
    float* __restrict__ out) {
  int e = blockIdx.z;
  int cnt = g_cnt[e];
  int y0 = blockIdx.y * 128;
  if (y0 >= cnt) return;
  int offE = g_off[e];
  int n0 = (blockIdx.x & 7) * 128;
  int ks = blockIdx.x >> 3;
  __shared__ short As[128 * 32];
  __shared__ short Bs[128 * 32];
  __shared__ int toks[128];
  __shared__ float gls[128];
  int tid = threadIdx.x;
  if (tid < 128) {
    int ic = min(y0 + tid, cnt - 1);
    toks[tid] = list[offE + ic];
    gls[tid] = gl[offE + ic];
  }
  int lane = tid & 63, w = tid >> 6;
  int rl = lane >> 2, sl = lane & 3;
  int rA0 = (w * 2 + 0) * 16 + rl, rA1 = (w * 2 + 1) * 16 + rl;
  int cA0 = sl ^ ((rA0 >> 1) & 3), cA1 = sl ^ ((rA1 >> 1) & 3);
  int p0 = offE + min(y0 + rA0, cnt - 1);
  int p1 = offE + min(y0 + rA1, cnt - 1);
  const bf16* gA0 = hidden + (size_t)p0 * FF + ks * 2048 + cA0 * 8;
  const bf16* gA1 = hidden + (size_t)p1 * FF + ks * 2048 + cA1 * 8;
  const bf16* WtE = Wt + (size_t)e * CC * FF;
  const bf16* gB0 = WtE + (size_t)(n0 + rA0) * FF + ks * 2048 + cA0 * 8;
  const bf16* gB1 = WtE + (size_t)(n0 + rA1) * FF + ks * 2048 + cA1 * 8;
  void* lA0 = &As[(w * 2 + 0) * 512]; void* lA1 = &As[(w * 2 + 1) * 512];
  void* lB0 = &Bs[(w * 2 + 0) * 512]; void* lB1 = &Bs[(w * 2 + 1) * 512];
  int wr = w >> 1, wc = w & 1;
  int mr = lane & 15, q = lane >> 4;
  int co = (q ^ ((mr >> 1) & 3)) * 8;
  int aoff = (wr * 64 + mr) * 32 + co;
  int boff = (wc * 64 + mr) * 32 + co;
  f32x4 z = {0.f, 0.f, 0.f, 0.f};
  f32x4 acc[4][4];
#pragma unroll
  for (int i = 0; i < 4; ++i)
#pragma unroll
    for (int j = 0; j < 4; ++j) acc[i][j] = z;
  for (int k0 = 0; k0 < 2048; k0 += 32) {
    __syncthreads();
    g2l16(gA0 + k0, lA0);
    g2l16(gA1 + k0, lA1);
    g2l16(gB0 + k0, lB0);
    g2l16(gB1 + k0, lB1);
    __syncthreads();
    bf16x8 a[4], b[4];
#pragma unroll
    for (int i = 0; i < 4; ++i) a[i] = *(const bf16x8*)&As[aoff + i * 512];
#pragma unroll
    for (int j = 0; j < 4; ++j) b[j] = *(const bf16x8*)&Bs[boff + j * 512];
#pragma unroll
    for (int i = 0; i < 4; ++i)
#pragma unroll
      for (int j = 0; j < 4; ++j)
        acc[i][j] = __builtin_amdgcn_mfma_f32_16x16x32_bf16(a[i], b[j], acc[i][j], 0, 0, 0);
  }
  int lr = lane >> 4;
#pragma unroll
  for (int j = 0; j < 4; ++j) {
    int n = n0 + wc * 64 + j * 16 + mr;
    float b2v = (ks == 0) ? b2[(size_t)e * CC + n] : 0.f;
#pragma unroll
    for (int i = 0; i < 4; ++i) {
#pragma unroll
      for (int r = 0; r < 4; ++r) {
        int lm = wr * 64 + i * 16 + lr * 4 + r;
        int m = y0 + lm;
        if (m < cnt) {
          int tok = toks[lm];
          float gv = gls[lm];
          atomicAdd(&out[(size_t)tok * CC + n], gv * (acc[i][j][r] + b2v));
        }
      }
    }
  }
}

extern "C" void kernel_launch(void* const* d_in, const int* in_sizes, int n_in,
                              void* d_out, int out_size, void* d_ws, size_t ws_size,
                              hipStream_t stream) {
  (void)in_sizes; (void)n_in; (void)out_size; (void)ws_size;
  const float* x     = (const float*)d_in[0];
  const float* noise = (const float*)d_in[1];
  const float* ln1_g = (const float*)d_in[2];
  const float* ln1_b = (const float*)d_in[3];
  const float* ln2_g = (const float*)d_in[4];
  const float* ln2_b = (const float*)d_in[5];
  const float* Wq    = (const float*)d_in[6];
  const float* Wk    = (const float*)d_in[7];
  const float* Wv    = (const float*)d_in[8];
  const float* Wproj = (const float*)d_in[9];
  const float* bproj = (const float*)d_in[10];
  const float* Wr    = (const float*)d_in[11];
  const float* br    = (const float*)d_in[12];
  const float* Wn    = (const float*)d_in[13];
  const float* bn    = (const float*)d_in[14];
  const float* W1    = (const float*)d_in[15];
  const float* b1    = (const float*)d_in[16];
  const float* W2    = (const float*)d_in[17];
  const float* b2    = (const float*)d_in[18];
  float* out = (float*)d_out;
  char* W = (char*)d_ws;
  const size_t MB = 1024 * 1024;

  bf16* xnhi  = (bf16*)(W + 0 * MB);     // 4 MB
  bf16* xnlo  = (bf16*)(W + 4 * MB);
  bf16* xn2b  = (bf16*)(W + 8 * MB);
  bf16* qhi   = (bf16*)(W + 12 * MB);
  bf16* qlo   = (bf16*)(W + 16 * MB);
  bf16* khi   = (bf16*)(W + 20 * MB);
  bf16* klo   = (bf16*)(W + 24 * MB);
  bf16* vthi  = (bf16*)(W + 28 * MB);
  bf16* vtlo  = (bf16*)(W + 32 * MB);
  bf16* atthi = (bf16*)(W + 36 * MB);
  bf16* attlo = (bf16*)(W + 40 * MB);
  bf16* hidden = (bf16*)(W + 12 * MB);   // 32 MB, overlaps q..att (dead after proj/router)
  bf16* wbh   = (bf16*)(W + 44 * MB);    // Wqkvt hi 6 MB
  bf16* wbl   = (bf16*)(W + 50 * MB);    // Wqkvt lo 6 MB
  bf16* wph   = (bf16*)(W + 56 * MB);    // Wpt hi 2 MB
  bf16* wpl   = (bf16*)(W + 58 * MB);    // Wpt lo 2 MB
  bf16* Wt    = (bf16*)(W + 44 * MB);    // 64 MB for MoE (after proj)
  char* S = W + 108 * MB;
  int*   topi = (int*)S;
  float* gval = (float*)(S + 16384);
  int*   list = (int*)(S + 32768);
  float* gl   = (float*)(S + 49152);
  int*   gcnt = (int*)(S + 65536);
  int*   goff = gcnt + 8;

  // weight transposes+splits for attention path
  trsplit_kernel<<<dim3(2, 32, 16), dim3(32, 8), 0, stream>>>(Wq, wbh, wbl, CC, DD, (long)CC * DD, (long)DD * CC);
  trsplit_kernel<<<dim3(2, 32, 16), dim3(32, 8), 0, stream>>>(Wk, wbh + 1024 * 1024, wbl + 1024 * 1024, CC, DD, (long)CC * DD, (long)DD * CC);
  trsplit_kernel<<<dim3(2, 32, 16), dim3(32, 8), 0, stream>>>(Wv, wbh + 2048 * 1024, wbl + 2048 * 1024, CC, DD, (long)CC * DD, (long)DD * CC);
  trsplit_kernel<<<dim3(32, 32, 1), dim3(32, 8), 0, stream>>>(Wproj, wph, wpl, CC, CC, 0, 0);

  ln_kernel<<<TT, 256, 0, stream>>>(x, ln1_g, ln1_b, nullptr, xnhi, xnlo);
  qkv_mfma<<<dim3(24, 16), 256, 0, stream>>>(xnhi, xnlo, wbh, wbl, qhi, qlo, khi, klo, vthi, vtlo);
  attn_mfma<<<dim3(32, HH), 256, 0, stream>>>(qhi, qlo, khi, klo, vthi, vtlo, atthi, attlo);
  proj_mfma<<<dim3(8, 16), 256, 0, stream>>>(atthi, attlo, wph, wpl, bproj, x, out);

  ln_kernel<<<TT, 256, 0, stream>>>(out, ln2_g, ln2_b, xn2b, nullptr, nullptr);
  router_kernel<<<TT, 64, 0, stream>>>(out, ln2_g, ln2_b, Wr, br, Wn, bn, noise, topi, gval);
  scan_fill_kernel<<<1, 256, 0, stream>>>(topi, gval, gcnt, goff, list, gl);

  tr_cast_kernel<<<dim3(FF / 32, CC / 32, EE), dim3(32, 8), 0, stream>>>(W1, Wt, CC, FF);
  moe1_mfma<<<dim3(FF / 128, TT / 128, EE), 256, 0, stream>>>(xn2b, Wt, b1, gcnt, goff, list, hidden);
  tr_cast_kernel<<<dim3(CC / 32, FF / 32, EE), dim3(32, 8), 0, stream>>>(W2, Wt, FF, CC);
  moe2_mfma<<<dim3(16, TT / 128, EE), 256, 0, stream>>>(hidden, Wt, b2, gcnt, goff, list, gl, out);
}